// Round 13
// baseline (197.349 us; speedup 1.0000x reference)
//
#include <hip/hip_runtime.h>
#include <hip/hip_bf16.h>
#include <cstdint>
#include <cstddef>

typedef __hip_bfloat16 bf16;
typedef __attribute__((ext_vector_type(8))) short short8;
typedef __attribute__((ext_vector_type(4))) float floatx4;

#define KO 15360
#define KS 16
#define KSLICE 960          /* KO / KS, multiple of 64 */
#define NIT (KSLICE / 64)   /* 15 */

__device__ __forceinline__ float lrelu(float v) { return v > 0.f ? v : 0.01f * v; }

__device__ __forceinline__ float bflo(unsigned int u) {
  unsigned int x = u << 16; float f; __builtin_memcpy(&f, &x, 4); return f;
}
__device__ __forceinline__ float bfhi(unsigned int u) {
  unsigned int x = u & 0xffff0000u; float f; __builtin_memcpy(&f, &x, 4); return f;
}
__device__ __forceinline__ unsigned int pk2(float lo, float hi) {
  bf16 a = __float2bfloat16(lo), b = __float2bfloat16(hi);
  unsigned short ua, ub;
  __builtin_memcpy(&ua, &a, 2); __builtin_memcpy(&ub, &b, 2);
  return (unsigned int)ua | ((unsigned int)ub << 16);
}
__device__ __forceinline__ unsigned int hpair(unsigned int u, unsigned int v) {
  return pk2(lrelu(bflo(u) + bflo(v)), lrelu(bfhi(u) + bfhi(v)));
}

// async 16B global -> LDS (no VGPR round-trip; per-wave dest = uniform base + lane*16)
__device__ __forceinline__ void async_lds16(const bf16* g, bf16* l) {
  __builtin_amdgcn_global_load_lds((__attribute__((address_space(1))) void*)(g),
                                   (__attribute__((address_space(3))) void*)(l),
                                   16, 0, 0);
}

// ---- K0 prep: role-dispatched merge of pack_hidden (blocks 0..15) and
//      out_W transpose+convert (blocks 16..975).
__global__ __launch_bounds__(256) void prep(
    const float* __restrict__ hidden_W, bf16* __restrict__ hWtp,
    const float* __restrict__ out_W, bf16* __restrict__ oWt)
{
  __shared__ float sbuf[64 * 65];
  const int t = threadIdx.x;
  const int id = blockIdx.x;

  if (id < 16) {
    // pack hidden_W (256x256 f32, k-major) into MFMA-B-frag order:
    // P[((g*8+ks)*64+l)*8 + j] = W[ks*32+(l>>4)*8+j][g*16+(l&15)]
    const int g = id;
    float* Lt = sbuf;
    for (int i = t; i < 4096; i += 256)
      Lt[i] = hidden_W[(size_t)(i >> 4) * 256 + g * 16 + (i & 15)];
    __syncthreads();
    #pragma unroll
    for (int cc = 0; cc < 2; ++cc) {
      int c = t + 256 * cc;
      int ks = c >> 6, l = c & 63, lr = l & 15, quad = l >> 4;
      short8 v;
      #pragma unroll
      for (int j = 0; j < 8; ++j) {
        bf16 b = __float2bfloat16(Lt[(ks * 32 + quad * 8 + j) * 16 + lr]);
        short s; __builtin_memcpy(&s, &b, 2);
        v[j] = s;
      }
      *(short8*)(hWtp + ((size_t)(g * 8 + ks) * 64 + l) * 8) = v;
    }
  } else {
    const int id2 = id - 16;
    const int kb = (id2 % 240) * 64;
    const int nb = (id2 / 240) * 64;
    float (*tile)[65] = (float(*)[65])sbuf;
    #pragma unroll
    for (int i = 0; i < 16; ++i) {
      int idx = t + 256 * i;
      int r = idx >> 6, c = idx & 63;
      tile[r][c] = out_W[(size_t)(kb + r) * 256 + nb + c];
    }
    __syncthreads();
    #pragma unroll
    for (int i = 0; i < 16; ++i) {
      int idx = t + 256 * i;
      int r = idx >> 6, c = idx & 63;
      oWt[(size_t)(nb + r) * KO + kb + c] = __float2bfloat16(tile[c][r]);
    }
  }
}

// ---- K1 hb_uv: fused hero/board VALU + hidden GEMM, no Abuf round-trip.
//      Phase 1: At[4 items] in LDS. Phase 2: hWtp streamed in 32 KB n-quarters
//      into the dead weight region (union). Wave = item. No persistent VGPR hog.
__global__ __launch_bounds__(256, 2) void hb_uv(
    const int* __restrict__ x, const float* __restrict__ card_emb,
    const float* __restrict__ hand_W, const float* __restrict__ hand_b,
    const float* __restrict__ board_W, const float* __restrict__ board_b,
    const bf16* __restrict__ hWtp, const float* __restrict__ hidden_b,
    bf16* __restrict__ UV)
{
  static constexpr int H0[6] = {0,0,0,1,1,2};
  static constexpr int H1[6] = {1,2,3,2,3,3};
  static constexpr int B0[10] = {0,0,0,0,0,0,1,1,1,2};
  static constexpr int B1[10] = {1,1,1,2,2,3,2,2,3,3};
  static constexpr int B2[10] = {2,3,4,3,4,4,3,4,4,4};

  __shared__ __align__(16) char uni[40960];  // ph1: wH 16K + wB 24K | ph2: hQ 32K
  __shared__ float bH[128], bB[128], biasH[256];
  __shared__ float emb[4][9][16];
  __shared__ bf16 At[4][16][264];            // 33 KB

  float* wH = (float*)uni;
  float* wB = (float*)(uni + 16384);
  bf16*  hQ = (bf16*)uni;

  const int t = threadIdx.x;
  const int w = t >> 6, l = t & 63, lr = l & 15, quad = l >> 4;
  const int item0 = blockIdx.x * 4;

  // ---- stage weights, biases, embeddings
  for (int i = t * 4; i < 4096; i += 1024) *(float4*)&wH[i] = *(const float4*)&hand_W[i];
  for (int i = t * 4; i < 6144; i += 1024) *(float4*)&wB[i] = *(const float4*)&board_W[i];
  if (t < 128) { bH[t] = hand_b[t]; bB[t] = board_b[t]; }
  biasH[t] = hidden_b[t];
  for (int ii = t; ii < 576; ii += 256) {
    int li = ii / 144, idx = ii - li * 144;
    int ci = idx >> 4, e = idx & 15;
    int rk = x[(item0 + li) * 18 + 2 * ci], st = x[(item0 + li) * 18 + 2 * ci + 1];
    int card = (rk > 0 ? rk - 1 : 0) + (st > 0 ? (st - 1) * 13 : 0);
    emb[li][ci][e] = card_emb[card * 16 + e];
  }
  __syncthreads();

  // ---- phase 1: hero/board VALU -> At[4] (threads 0-127: items 0,2; 128-255: 1,3)
  const int half = t >> 7, j = t & 127;
  #pragma unroll
  for (int pass = 0; pass < 2; ++pass) {
    const int li = 2 * pass + half;
    {
      bf16 z = __float2bfloat16(0.f);
      #pragma unroll
      for (int p = 0; p < 6; ++p) At[li][p][128 + j] = z;
      #pragma unroll
      for (int b = 0; b < 10; ++b) At[li][6 + b][j] = z;
    }
    float aH[6], aB[10];
    {
      float hb = bH[j], bb = bB[j];
      #pragma unroll
      for (int p = 0; p < 6; ++p) aH[p] = hb;
      #pragma unroll
      for (int b = 0; b < 10; ++b) aB[b] = bb;
    }
    #pragma unroll
    for (int k = 0; k < 16; ++k) {
      float e[9];
      #pragma unroll
      for (int c = 0; c < 9; ++c) e[c] = emb[li][c][k];
      float w0 = wH[k * 128 + j], w1 = wH[(16 + k) * 128 + j];
      float v0 = wB[k * 128 + j], v1 = wB[(16 + k) * 128 + j], v2 = wB[(32 + k) * 128 + j];
      #pragma unroll
      for (int p = 0; p < 6; ++p)
        aH[p] += e[H0[p]] * w0 + e[H1[p]] * w1;
      #pragma unroll
      for (int b = 0; b < 10; ++b)
        aB[b] += e[4 + B0[b]] * v0 + e[4 + B1[b]] * v1 + e[4 + B2[b]] * v2;
    }
    #pragma unroll
    for (int p = 0; p < 6; ++p) At[li][p][j] = __float2bfloat16(lrelu(aH[p]));
    #pragma unroll
    for (int b = 0; b < 10; ++b) At[li][6 + b][128 + j] = __float2bfloat16(lrelu(aB[b]));
  }
  __syncthreads();   // At final; all wH/wB reads done (uni reusable)

  // ---- phase 2: hidden GEMM. a-frags once; hWtp streamed in 4 n-quarters.
  short8 a[8];
  #pragma unroll
  for (int ks = 0; ks < 8; ++ks)
    a[ks] = *(const short8*)&At[w][lr][ks * 32 + quad * 8];

  bf16* dst = UV + (size_t)(item0 + w) * 4096;

  for (int q = 0; q < 4; ++q) {
    if (q) __syncthreads();            // prior quarter's hQ reads done
    #pragma unroll
    for (int i = 0; i < 8; ++i)
      async_lds16(hWtp + (size_t)q * 16384 + (size_t)(i * 256 + t) * 8,
                  hQ + (size_t)(i * 256 + t) * 8);
    __syncthreads();                   // drain asyncs

    #pragma unroll
    for (int tl = 0; tl < 4; ++tl) {
      floatx4 acc = {0.f, 0.f, 0.f, 0.f};
      #pragma unroll
      for (int ks = 0; ks < 8; ++ks) {
        short8 bfr = *(const short8*)&hQ[(size_t)((tl * 8 + ks) * 64 + l) * 8];
        acc = __builtin_amdgcn_mfma_f32_16x16x32_bf16(a[ks], bfr, acc, 0, 0, 0);
      }
      int n = q * 64 + tl * 16 + lr;
      float bn = biasH[n];
      #pragma unroll
      for (int r = 0; r < 4; ++r) {
        int m = quad * 4 + r;
        dst[m * 256 + n] = __float2bfloat16(acc[r] + (m >= 6 ? bn : 0.f));
      }
    }
  }
}

// uu/vv fetch for out_gemm iteration `it`
__device__ __forceinline__ void uv_fetch(const bf16* __restrict__ UV, int m0, int ar,
                                         int ac, int ks0, int it,
                                         uint4& u0, uint4& u1, uint4& v0, uint4& v1)
{
  const int gk = ks0 + it * 64;
  const int combo = gk >> 8;                    // wave-uniform
  const int urow = combo / 10, vrow = 6 + (combo - urow * 10);
  const int c0 = gk & 255;
  const bf16* ub = UV + ((size_t)(m0 + ar) * 16 + urow) * 256 + c0 + ac * 16;
  const bf16* vb = UV + ((size_t)(m0 + ar) * 16 + vrow) * 256 + c0 + ac * 16;
  u0 = *(const uint4*)ub;  u1 = *(const uint4*)(ub + 8);
  v0 = *(const uint4*)vb;  v1 = *(const uint4*)(vb + 8);
}

// ---- K2: out GEMM, split-K. Single-buffer 2-barrier (proven); async Bs staging;
//      XCD-locality swizzle.
__global__ __launch_bounds__(256, 2) void out_gemm(
    const bf16* __restrict__ UV, const bf16* __restrict__ Wt,
    float* __restrict__ pbuf)
{
  __shared__ bf16 As[64 * 64];
  __shared__ bf16 Bs[256 * 64];

  const int t = threadIdx.x;
  const int id = blockIdx.x;
  const int by = ((id & 7) << 1) | ((id >> 3) & 1);
  const int bx = id >> 4;
  const int w = t >> 6, l = t & 63, lr = l & 15, quad = l >> 4;
  const int m0 = bx * 64;
  const int ks0 = by * KSLICE;
  const int ar = t >> 2, ac = t & 3;

  const bf16* rowp[8];
  {
    int rl = l >> 3, j = (l & 7) ^ rl;
    #pragma unroll
    for (int q = 0; q < 8; ++q)
      rowp[q] = Wt + (size_t)(w * 64 + 8 * q + rl) * KO + ks0 + j * 8;
  }
  bf16* BsW = &Bs[w * 4096];

  floatx4 acc[16];
  floatx4 zero = {0.f, 0.f, 0.f, 0.f};
  #pragma unroll
  for (int i = 0; i < 16; ++i) acc[i] = zero;

  uint4 cu0, cu1, cv0, cv1;
  uv_fetch(UV, m0, ar, ac, ks0, 0, cu0, cu1, cv0, cv1);

  for (int it = 0; it < NIT; ++it) {
    __syncthreads();

    #pragma unroll
    for (int q = 0; q < 8; ++q)
      async_lds16(rowp[q] + it * 64, BsW + q * 512);

    {
      uint4 h0, h1;
      h0.x = hpair(cu0.x, cv0.x); h0.y = hpair(cu0.y, cv0.y);
      h0.z = hpair(cu0.z, cv0.z); h0.w = hpair(cu0.w, cv0.w);
      h1.x = hpair(cu1.x, cv1.x); h1.y = hpair(cu1.y, cv1.y);
      h1.z = hpair(cu1.z, cv1.z); h1.w = hpair(cu1.w, cv1.w);
      int jA0 = (2 * ac) ^ (ar & 7);
      int jA1 = (2 * ac + 1) ^ (ar & 7);
      *(uint4*)&As[ar * 64 + jA0 * 8] = h0;
      *(uint4*)&As[ar * 64 + jA1 * 8] = h1;
    }

    __syncthreads();

    if (it + 1 < NIT)
      uv_fetch(UV, m0, ar, ac, ks0, it + 1, cu0, cu1, cv0, cv1);

    #pragma unroll
    for (int ks = 0; ks < 2; ++ks) {
      short8 af[4], bfr[4];
      #pragma unroll
      for (int i = 0; i < 4; ++i) {
        int row = i * 16 + lr;
        int jp = (4 * ks + quad) ^ (row & 7);
        af[i] = *(const short8*)&As[row * 64 + jp * 8];
      }
      #pragma unroll
      for (int j = 0; j < 4; ++j) {
        int row = w * 64 + j * 16 + lr;
        int jp = (4 * ks + quad) ^ (row & 7);
        bfr[j] = *(const short8*)&Bs[row * 64 + jp * 8];
      }
      #pragma unroll
      for (int i = 0; i < 4; ++i)
        #pragma unroll
        for (int j = 0; j < 4; ++j)
          acc[i * 4 + j] = __builtin_amdgcn_mfma_f32_16x16x32_bf16(af[i], bfr[j], acc[i * 4 + j], 0, 0, 0);
    }
  }

  float* dst = pbuf + (((size_t)by * 48 + bx) * 4 + w) * 4096 + l;
  #pragma unroll
  for (int a = 0; a < 16; ++a)
    #pragma unroll
    for (int r = 0; r < 4; ++r)
      dst[(a * 4 + r) * 64] = acc[a][r];
}

// ---- K3: reduce split-K partials (permuted layout) + bias + lrelu
__global__ __launch_bounds__(256) void reduce_bias(
    const float* __restrict__ pbuf, const float* __restrict__ outb,
    float* __restrict__ out, int slice_stride)
{
  int i4 = blockIdx.x * 256 + threadIdx.x;
  int idx = i4 * 4;
  float4 s = *(const float4*)&pbuf[idx];
  #pragma unroll
  for (int k = 1; k < KS; ++k) {
    float4 v = *(const float4*)&pbuf[idx + (size_t)k * slice_stride];
    s.x += v.x; s.y += v.y; s.z += v.z; s.w += v.w;
  }
  int l = idx & 63, q = (idx >> 6) & 63, w2 = (idx >> 12) & 3, bx = idx >> 14;
  int a = q >> 2, r = q & 3, i = a >> 2, tl = a & 3;
  int lr = l & 15, quad = l >> 4;
  int m = bx * 64 + i * 16 + quad * 4 + r;
  int n = w2 * 64 + tl * 16 + lr;
  float4 b = *(const float4*)&outb[n];
  float4 rr;
  rr.x = lrelu(s.x + b.x); rr.y = lrelu(s.y + b.y);
  rr.z = lrelu(s.z + b.z); rr.w = lrelu(s.w + b.w);
  *(float4*)&out[(size_t)m * 256 + n] = rr;
}

extern "C" void kernel_launch(void* const* d_in, const int* in_sizes, int n_in,
                              void* d_out, int out_size, void* d_ws, size_t ws_size,
                              hipStream_t stream)
{
  const int*   x        = (const int*)  d_in[0];
  const float* card_emb = (const float*)d_in[1];
  const float* hand_W   = (const float*)d_in[2];
  const float* hand_b   = (const float*)d_in[3];
  const float* board_W  = (const float*)d_in[4];
  const float* board_b  = (const float*)d_in[5];
  const float* hidden_W = (const float*)d_in[6];
  const float* hidden_b = (const float*)d_in[7];
  const float* out_W    = (const float*)d_in[8];
  const float* out_b    = (const float*)d_in[9];
  float* out = (float*)d_out;

  const int NI = in_sizes[0] / 18;   // 3072 items

  char* ws = (char*)d_ws;
  bf16* hWtp = (bf16*)ws;                                     // 128 KB (frag-packed)
  bf16* oWt  = (bf16*)(ws + 131072);                          // 7.5 MB
  bf16* UV   = (bf16*)(ws + 131072 + 7864320);                // NI*4096*2 = 24 MB
  float* pbuf = (float*)(ws + 131072 + 7864320 + (size_t)NI * 8192);  // 50.3 MB

  prep<<<16 + 240 * 4, 256, 0, stream>>>(hidden_W, hWtp, out_W, oWt);
  hb_uv<<<NI / 4, 256, 0, stream>>>(x, card_emb, hand_W, hand_b,
                                    board_W, board_b, hWtp, hidden_b, UV);
  out_gemm<<<NI / 64 * KS, 256, 0, stream>>>(UV, oWt, pbuf);
  reduce_bias<<<NI / 4, 256, 0, stream>>>(pbuf, out_b, out, NI * 256);
}

// Round 14
// 163.872 us; speedup vs baseline: 1.2043x; 1.2043x over previous
//
#include <hip/hip_runtime.h>
#include <hip/hip_bf16.h>
#include <cstdint>
#include <cstddef>

typedef __hip_bfloat16 bf16;
typedef __attribute__((ext_vector_type(8))) short short8;
typedef __attribute__((ext_vector_type(4))) float floatx4;

#define KO 15360
#define KS 16
#define KSLICE 960          /* KO / KS, multiple of 64 */
#define NIT (KSLICE / 64)   /* 15 */
#define IPB 12              /* items per uv_gemm block */

__device__ __forceinline__ float lrelu(float v) { return v > 0.f ? v : 0.01f * v; }

__device__ __forceinline__ float bflo(unsigned int u) {
  unsigned int x = u << 16; float f; __builtin_memcpy(&f, &x, 4); return f;
}
__device__ __forceinline__ float bfhi(unsigned int u) {
  unsigned int x = u & 0xffff0000u; float f; __builtin_memcpy(&f, &x, 4); return f;
}
__device__ __forceinline__ unsigned int pk2(float lo, float hi) {
  bf16 a = __float2bfloat16(lo), b = __float2bfloat16(hi);
  unsigned short ua, ub;
  __builtin_memcpy(&ua, &a, 2); __builtin_memcpy(&ub, &b, 2);
  return (unsigned int)ua | ((unsigned int)ub << 16);
}
__device__ __forceinline__ unsigned int hpair(unsigned int u, unsigned int v) {
  return pk2(lrelu(bflo(u) + bflo(v)), lrelu(bfhi(u) + bfhi(v)));
}

// async 16B global -> LDS (no VGPR round-trip; dest = wave-uniform base + lane*16)
__device__ __forceinline__ void async_lds16(const bf16* g, bf16* l) {
  __builtin_amdgcn_global_load_lds((__attribute__((address_space(1))) void*)(g),
                                   (__attribute__((address_space(3))) void*)(l),
                                   16, 0, 0);
}

// ---- K1 stage1: role-dispatched merge of hb_pack (blocks 0..NB_HB-1),
//      pack_hidden (NB_HB..NB_HB+15), out_W transpose (rest). All independent.
#define NB_HB 768
__global__ __launch_bounds__(256) void stage1(
    const int* __restrict__ x, const float* __restrict__ card_emb,
    const float* __restrict__ hand_W, const float* __restrict__ hand_b,
    const float* __restrict__ board_W, const float* __restrict__ board_b,
    bf16* __restrict__ Abuf,
    const float* __restrict__ hidden_W, bf16* __restrict__ hWtp,
    const float* __restrict__ out_W, bf16* __restrict__ oWt)
{
  static constexpr int H0[6] = {0,0,0,1,1,2};
  static constexpr int H1[6] = {1,2,3,2,3,3};
  static constexpr int B0[10] = {0,0,0,0,0,0,1,1,1,2};
  static constexpr int B1[10] = {1,1,1,2,2,3,2,2,3,3};
  static constexpr int B2[10] = {2,3,4,3,4,4,3,4,4,4};

  __shared__ __align__(16) char smem[61696];
  const int t = threadIdx.x;
  const int id = blockIdx.x;

  if (id < NB_HB) {
    // ---------------- hb_pack role (round-10/12 proven) ----------------
    float* wH = (float*)smem;                    // 16384 B
    float* wB = (float*)(smem + 16384);          // 24576 B
    float* bH = (float*)(smem + 40960);          // 512 B
    float* bB = (float*)(smem + 41472);          // 512 B
    float (*emb)[9][16] = (float(*)[9][16])(smem + 41984);   // 2304 B
    bf16 (*At)[16][264] = (bf16(*)[16][264])(smem + 44288);  // 16896 B

    const int item0 = id * 4;

    for (int i = t * 4; i < 4096; i += 1024) *(float4*)&wH[i] = *(const float4*)&hand_W[i];
    for (int i = t * 4; i < 6144; i += 1024) *(float4*)&wB[i] = *(const float4*)&board_W[i];
    if (t < 128) { bH[t] = hand_b[t]; bB[t] = board_b[t]; }
    for (int ii = t; ii < 576; ii += 256) {
      int li = ii / 144, idx = ii - li * 144;
      int ci = idx >> 4, e = idx & 15;
      int rk = x[(item0 + li) * 18 + 2 * ci], st = x[(item0 + li) * 18 + 2 * ci + 1];
      int card = (rk > 0 ? rk - 1 : 0) + (st > 0 ? (st - 1) * 13 : 0);
      emb[li][ci][e] = card_emb[card * 16 + e];
    }
    __syncthreads();

    const int half = t >> 7, j = t & 127;

    for (int pass = 0; pass < 2; ++pass) {
      if (pass) __syncthreads();
      const int embi = 2 * pass + half;
      {
        bf16 z = __float2bfloat16(0.f);
        #pragma unroll
        for (int p = 0; p < 6; ++p) At[half][p][128 + j] = z;
        #pragma unroll
        for (int b = 0; b < 10; ++b) At[half][6 + b][j] = z;
      }
      float aH[6], aB[10];
      {
        float hb = bH[j], bb = bB[j];
        #pragma unroll
        for (int p = 0; p < 6; ++p) aH[p] = hb;
        #pragma unroll
        for (int b = 0; b < 10; ++b) aB[b] = bb;
      }
      #pragma unroll
      for (int k = 0; k < 16; ++k) {
        float e[9];
        #pragma unroll
        for (int c = 0; c < 9; ++c) e[c] = emb[embi][c][k];
        float w0 = wH[k * 128 + j], w1 = wH[(16 + k) * 128 + j];
        float v0 = wB[k * 128 + j], v1 = wB[(16 + k) * 128 + j], v2 = wB[(32 + k) * 128 + j];
        #pragma unroll
        for (int p = 0; p < 6; ++p)
          aH[p] += e[H0[p]] * w0 + e[H1[p]] * w1;
        #pragma unroll
        for (int b = 0; b < 10; ++b)
          aB[b] += e[4 + B0[b]] * v0 + e[4 + B1[b]] * v1 + e[4 + B2[b]] * v2;
      }
      #pragma unroll
      for (int p = 0; p < 6; ++p) At[half][p][j] = __float2bfloat16(lrelu(aH[p]));
      #pragma unroll
      for (int b = 0; b < 10; ++b) At[half][6 + b][128 + j] = __float2bfloat16(lrelu(aB[b]));
      __syncthreads();

      #pragma unroll
      for (int li2 = 0; li2 < 2; ++li2) {
        #pragma unroll
        for (int cc = 0; cc < 2; ++cc) {
          int c = t + 256 * cc;
          int m = c & 15, kq = (c >> 4) & 3, ks = c >> 6;
          short8 v = *(const short8*)&At[li2][m][ks * 32 + kq * 8];
          *(short8*)(Abuf + (size_t)(item0 + 2 * pass + li2) * 4096 + (size_t)c * 8) = v;
        }
      }
      __syncthreads();
    }
  } else if (id < NB_HB + 16) {
    // ---------------- pack_hidden role ----------------
    // P[((g*8+ks)*64+l)*8 + j] = W[ks*32+(l>>4)*8+j][g*16+(l&15)]
    const int g = id - NB_HB;
    float* Lt = (float*)smem;
    for (int i = t; i < 4096; i += 256)
      Lt[i] = hidden_W[(size_t)(i >> 4) * 256 + g * 16 + (i & 15)];
    __syncthreads();
    #pragma unroll
    for (int cc = 0; cc < 2; ++cc) {
      int c = t + 256 * cc;
      int ks = c >> 6, l = c & 63, lr = l & 15, quad = l >> 4;
      short8 v;
      #pragma unroll
      for (int j = 0; j < 8; ++j) {
        bf16 b = __float2bfloat16(Lt[(ks * 32 + quad * 8 + j) * 16 + lr]);
        short s; __builtin_memcpy(&s, &b, 2);
        v[j] = s;
      }
      *(short8*)(hWtp + ((size_t)(g * 8 + ks) * 64 + l) * 8) = v;
    }
  } else {
    // ---------------- out_W transpose role ----------------
    const int id2 = id - NB_HB - 16;
    const int kb = (id2 % 240) * 64;
    const int nb = (id2 / 240) * 64;
    float (*tile)[65] = (float(*)[65])smem;
    #pragma unroll
    for (int i = 0; i < 16; ++i) {
      int idx = t + 256 * i;
      int r = idx >> 6, c = idx & 63;
      tile[r][c] = out_W[(size_t)(kb + r) * 256 + nb + c];
    }
    __syncthreads();
    #pragma unroll
    for (int i = 0; i < 16; ++i) {
      int idx = t + 256 * i;
      int r = idx >> 6, c = idx & 63;
      oWt[(size_t)(nb + r) * KO + kb + c] = __float2bfloat16(tile[c][r]);
    }
  }
}

// ---- K2: hidden GEMM; hWtp B-frags staged in LDS (64 KB = one n-half),
//      items in pairs sharing each B-frag ds_read.  (round-12 proven)
__global__ __launch_bounds__(256, 2) void uv_gemm(
    const bf16* __restrict__ Abuf, const bf16* __restrict__ hWtp,
    const float* __restrict__ hidden_b, bf16* __restrict__ UV)
{
  __shared__ bf16 hL[32768];

  const int t = threadIdx.x, w = t >> 6, l = t & 63;
  const int lr = l & 15, quad = l >> 4;
  const int half = blockIdx.y;
  const int item0 = blockIdx.x * IPB;

  const bf16* src = hWtp + (size_t)half * 32768;
  #pragma unroll
  for (int i = 0; i < 16; ++i)
    async_lds16(src + (size_t)(i * 256 + t) * 8, hL + (size_t)(i * 256 + t) * 8);

  float bias[2];
  #pragma unroll
  for (int tl = 0; tl < 2; ++tl)
    bias[tl] = hidden_b[half * 128 + (w * 2 + tl) * 16 + lr];

  __syncthreads();

  for (int ip = 0; ip < IPB / 2; ++ip) {
    const bf16* abA = Abuf + (size_t)(item0 + 2 * ip) * 4096;
    const bf16* abB = abA + 4096;
    short8 aA[8], aB[8];
    #pragma unroll
    for (int ks = 0; ks < 8; ++ks) {
      aA[ks] = *(const short8*)(abA + (size_t)(ks * 64 + l) * 8);
      aB[ks] = *(const short8*)(abB + (size_t)(ks * 64 + l) * 8);
    }

    floatx4 accA[2], accB[2];
    floatx4 zero = {0.f, 0.f, 0.f, 0.f};
    #pragma unroll
    for (int i = 0; i < 2; ++i) { accA[i] = zero; accB[i] = zero; }

    #pragma unroll
    for (int tl = 0; tl < 2; ++tl)
      #pragma unroll
      for (int ks = 0; ks < 8; ++ks) {
        short8 bfr = *(const short8*)&hL[(size_t)(((w * 2 + tl) * 8 + ks) * 64 + l) * 8];
        accA[tl] = __builtin_amdgcn_mfma_f32_16x16x32_bf16(aA[ks], bfr, accA[tl], 0, 0, 0);
        accB[tl] = __builtin_amdgcn_mfma_f32_16x16x32_bf16(aB[ks], bfr, accB[tl], 0, 0, 0);
      }

    #pragma unroll
    for (int li = 0; li < 2; ++li) {
      bf16* dst = UV + (size_t)(item0 + 2 * ip + li) * 4096;
      #pragma unroll
      for (int tl = 0; tl < 2; ++tl) {
        int n = half * 128 + (w * 2 + tl) * 16 + lr;
        floatx4 acc = li ? accB[tl] : accA[tl];
        #pragma unroll
        for (int r = 0; r < 4; ++r) {
          int m = quad * 4 + r;
          float v = acc[r] + (m >= 6 ? bias[tl] : 0.f);
          dst[m * 256 + n] = __float2bfloat16(v);
        }
      }
    }
  }
}

// uu/vv fetch for out_gemm iteration `it`
__device__ __forceinline__ void uv_fetch(const bf16* __restrict__ UV, int m0, int ar,
                                         int ac, int ks0, int it,
                                         uint4& u0, uint4& u1, uint4& v0, uint4& v1)
{
  const int gk = ks0 + it * 64;
  const int combo = gk >> 8;                    // wave-uniform
  const int urow = combo / 10, vrow = 6 + (combo - urow * 10);
  const int c0 = gk & 255;
  const bf16* ub = UV + ((size_t)(m0 + ar) * 16 + urow) * 256 + c0 + ac * 16;
  const bf16* vb = UV + ((size_t)(m0 + ar) * 16 + vrow) * 256 + c0 + ac * 16;
  u0 = *(const uint4*)ub;  u1 = *(const uint4*)(ub + 8);
  v0 = *(const uint4*)vb;  v1 = *(const uint4*)(vb + 8);
}

// ---- K3: out GEMM, split-K. Single-buffer 2-barrier (proven); async Bs staging;
//      XCD-locality swizzle.  (round-12 proven)
__global__ __launch_bounds__(256, 2) void out_gemm(
    const bf16* __restrict__ UV, const bf16* __restrict__ Wt,
    float* __restrict__ pbuf)
{
  __shared__ bf16 As[64 * 64];
  __shared__ bf16 Bs[256 * 64];

  const int t = threadIdx.x;
  const int id = blockIdx.x;
  const int by = ((id & 7) << 1) | ((id >> 3) & 1);
  const int bx = id >> 4;
  const int w = t >> 6, l = t & 63, lr = l & 15, quad = l >> 4;
  const int m0 = bx * 64;
  const int ks0 = by * KSLICE;
  const int ar = t >> 2, ac = t & 3;

  const bf16* rowp[8];
  {
    int rl = l >> 3, j = (l & 7) ^ rl;
    #pragma unroll
    for (int q = 0; q < 8; ++q)
      rowp[q] = Wt + (size_t)(w * 64 + 8 * q + rl) * KO + ks0 + j * 8;
  }
  bf16* BsW = &Bs[w * 4096];

  floatx4 acc[16];
  floatx4 zero = {0.f, 0.f, 0.f, 0.f};
  #pragma unroll
  for (int i = 0; i < 16; ++i) acc[i] = zero;

  uint4 cu0, cu1, cv0, cv1;
  uv_fetch(UV, m0, ar, ac, ks0, 0, cu0, cu1, cv0, cv1);

  for (int it = 0; it < NIT; ++it) {
    __syncthreads();

    #pragma unroll
    for (int q = 0; q < 8; ++q)
      async_lds16(rowp[q] + it * 64, BsW + q * 512);

    {
      uint4 h0, h1;
      h0.x = hpair(cu0.x, cv0.x); h0.y = hpair(cu0.y, cv0.y);
      h0.z = hpair(cu0.z, cv0.z); h0.w = hpair(cu0.w, cv0.w);
      h1.x = hpair(cu1.x, cv1.x); h1.y = hpair(cu1.y, cv1.y);
      h1.z = hpair(cu1.z, cv1.z); h1.w = hpair(cu1.w, cv1.w);
      int jA0 = (2 * ac) ^ (ar & 7);
      int jA1 = (2 * ac + 1) ^ (ar & 7);
      *(uint4*)&As[ar * 64 + jA0 * 8] = h0;
      *(uint4*)&As[ar * 64 + jA1 * 8] = h1;
    }

    __syncthreads();

    if (it + 1 < NIT)
      uv_fetch(UV, m0, ar, ac, ks0, it + 1, cu0, cu1, cv0, cv1);

    #pragma unroll
    for (int ks = 0; ks < 2; ++ks) {
      short8 af[4], bfr[4];
      #pragma unroll
      for (int i = 0; i < 4; ++i) {
        int row = i * 16 + lr;
        int jp = (4 * ks + quad) ^ (row & 7);
        af[i] = *(const short8*)&As[row * 64 + jp * 8];
      }
      #pragma unroll
      for (int j = 0; j < 4; ++j) {
        int row = w * 64 + j * 16 + lr;
        int jp = (4 * ks + quad) ^ (row & 7);
        bfr[j] = *(const short8*)&Bs[row * 64 + jp * 8];
      }
      #pragma unroll
      for (int i = 0; i < 4; ++i)
        #pragma unroll
        for (int j = 0; j < 4; ++j)
          acc[i * 4 + j] = __builtin_amdgcn_mfma_f32_16x16x32_bf16(af[i], bfr[j], acc[i * 4 + j], 0, 0, 0);
    }
  }

  float* dst = pbuf + (((size_t)by * 48 + bx) * 4 + w) * 4096 + l;
  #pragma unroll
  for (int a = 0; a < 16; ++a)
    #pragma unroll
    for (int r = 0; r < 4; ++r)
      dst[(a * 4 + r) * 64] = acc[a][r];
}

// ---- K4: reduce split-K partials (permuted layout) + bias + lrelu
__global__ __launch_bounds__(256) void reduce_bias(
    const float* __restrict__ pbuf, const float* __restrict__ outb,
    float* __restrict__ out, int slice_stride)
{
  int i4 = blockIdx.x * 256 + threadIdx.x;
  int idx = i4 * 4;
  float4 s = *(const float4*)&pbuf[idx];
  #pragma unroll
  for (int k = 1; k < KS; ++k) {
    float4 v = *(const float4*)&pbuf[idx + (size_t)k * slice_stride];
    s.x += v.x; s.y += v.y; s.z += v.z; s.w += v.w;
  }
  int l = idx & 63, q = (idx >> 6) & 63, w2 = (idx >> 12) & 3, bx = idx >> 14;
  int a = q >> 2, r = q & 3, i = a >> 2, tl = a & 3;
  int lr = l & 15, quad = l >> 4;
  int m = bx * 64 + i * 16 + quad * 4 + r;
  int n = w2 * 64 + tl * 16 + lr;
  float4 b = *(const float4*)&outb[n];
  float4 rr;
  rr.x = lrelu(s.x + b.x); rr.y = lrelu(s.y + b.y);
  rr.z = lrelu(s.z + b.z); rr.w = lrelu(s.w + b.w);
  *(float4*)&out[(size_t)m * 256 + n] = rr;
}

extern "C" void kernel_launch(void* const* d_in, const int* in_sizes, int n_in,
                              void* d_out, int out_size, void* d_ws, size_t ws_size,
                              hipStream_t stream)
{
  const int*   x        = (const int*)  d_in[0];
  const float* card_emb = (const float*)d_in[1];
  const float* hand_W   = (const float*)d_in[2];
  const float* hand_b   = (const float*)d_in[3];
  const float* board_W  = (const float*)d_in[4];
  const float* board_b  = (const float*)d_in[5];
  const float* hidden_W = (const float*)d_in[6];
  const float* hidden_b = (const float*)d_in[7];
  const float* out_W    = (const float*)d_in[8];
  const float* out_b    = (const float*)d_in[9];
  float* out = (float*)d_out;

  const int NI = in_sizes[0] / 18;   // 3072 items

  char* ws = (char*)d_ws;
  bf16* hWtp = (bf16*)ws;                                     // 128 KB (frag-packed)
  bf16* oWt  = (bf16*)(ws + 131072);                          // 7.5 MB
  bf16* UV   = (bf16*)(ws + 131072 + 7864320);                // NI*4096*2 = 24 MB
  bf16* Abuf = (bf16*)(ws + 131072 + 7864320 + (size_t)NI * 8192);   // 25.2 MB
  float* pbuf = (float*)Abuf;   // aliases Abuf (dead after uv_gemm): 50.3 MB

  stage1<<<NB_HB + 16 + 240 * 4, 256, 0, stream>>>(
      x, card_emb, hand_W, hand_b, board_W, board_b, Abuf,
      hidden_W, hWtp, out_W, oWt);
  uv_gemm<<<dim3(NI / IPB, 2), 256, 0, stream>>>(Abuf, hWtp, hidden_b, UV);
  out_gemm<<<NI / 64 * KS, 256, 0, stream>>>(UV, oWt, pbuf);
  reduce_bias<<<NI / 4, 256, 0, stream>>>(pbuf, out_b, out, NI * 256);
}